// Round 1
// baseline (191.349 us; speedup 1.0000x reference)
//
#include <hip/hip_runtime.h>
#include <stdint.h>

#define ZD 41
#define YD 1600
#define XD 1408
#define YXD (YD * XD)
#define NKEYS (ZD * YD * XD)          // 92,364,800 linear sites
#define BM_WORDS ((NKEYS + 63) / 64)  // 1,443,200 u64 words
#define BN_EPS 1e-3f

typedef unsigned long long u64;

// ---------------- ws layout ----------------
// [0, TBL*8)                    hash table: (key<<32)|idx, EMPTY = ~0ull
// [TBL*8, +BM_WORDS*8)          active-site bitmap
// [accum, +128)                 accum[0..15]=sum, accum[16..31]=sumsq
// (bitmap OOB-by-one reads land in accum region: in-bounds of ws, masked out)

__global__ void init_ws(u64* hash, u64* bitmap, float* accum, int tblSize) {
  int total = tblSize + BM_WORDS;
  for (int i = blockIdx.x * blockDim.x + threadIdx.x; i < total;
       i += gridDim.x * blockDim.x) {
    if (i < tblSize) hash[i] = ~0ull;
    else bitmap[i - tblSize] = 0ull;
  }
  if (blockIdx.x == 0 && threadIdx.x < 32) accum[threadIdx.x] = 0.f;
}

__global__ void build_hash(const int4* __restrict__ coords, u64* hash,
                           u64* bitmap, int n, int tblBits) {
  int i = blockIdx.x * blockDim.x + threadIdx.x;
  if (i >= n) return;
  int4 c = coords[i];  // (0, z, y, x)
  uint32_t key = (uint32_t)((c.y * YD + c.z) * XD + c.w);
  atomicOr(&bitmap[key >> 6], 1ull << (key & 63));
  uint32_t mask = (1u << tblBits) - 1u;
  uint32_t h = (key * 2654435761u) >> (32 - tblBits);
  u64 e = ((u64)key << 32) | (uint32_t)i;
  while (atomicCAS(&hash[h], ~0ull, e) != ~0ull) h = (h + 1) & mask;
}

__global__ void __launch_bounds__(256) subm_conv(
    const float4* __restrict__ feats, const int4* __restrict__ coords,
    const float* __restrict__ weight, const u64* __restrict__ hash,
    const u64* __restrict__ bitmap, float* __restrict__ out, int n,
    int tblBits) {
  __shared__ float wl[27 * 64];  // [k][c][o] = k*64 + c*16 + o
  for (int t = threadIdx.x; t < 27 * 64; t += 256) wl[t] = weight[t];
  __syncthreads();

  // Bijective XCD-chunk swizzle (m204): contiguous voxel ranges per XCD so
  // the sorted-key bitmap working set (~2MB) stays in the per-XCD 4MB L2.
  int B = gridDim.x;
  int q = B >> 3, r = B & 7;
  int xcd = blockIdx.x & 7, off = blockIdx.x >> 3;
  int sb = (xcd < r ? xcd * (q + 1) : r * (q + 1) + (xcd - r) * q) + off;
  int i = sb * 256 + (int)threadIdx.x;
  if (i >= n) return;

  int4 czyx = coords[i];
  int z = czyx.y, y = czyx.z, x = czyx.w;
  int key = (z * YD + y) * XD + x;

  float acc[16];
#pragma unroll
  for (int o = 0; o < 16; o++) acc[o] = 0.f;

  uint32_t hmask = (1u << tblBits) - 1u;
  int shift = 32 - tblBits;

#pragma unroll
  for (int dz = -1; dz <= 1; dz++) {
    if ((unsigned)(z + dz) >= (unsigned)ZD) continue;
#pragma unroll
    for (int dy = -1; dy <= 1; dy++) {
      if ((unsigned)(y + dy) >= (unsigned)YD) continue;
      int nb = key + dz * YXD + dy * XD;  // dx = 0 neighbor key
      // 3-bit window over keys {nb-1, nb, nb+1}
      int base = nb - 1;
      u64 w0 = bitmap[base >> 6];
      u64 w1 = bitmap[(nb + 1) >> 6];
      unsigned p = (unsigned)(base & 63);
      u64 win = (w0 >> p) | (p ? (w1 << (64 - p)) : 0ull);
      unsigned m = (unsigned)win & 7u;
      if (x == 0) m &= 6u;
      if (x == XD - 1) m &= 3u;
      while (m) {
        int b = __ffs(m) - 1;  // 0,1,2 -> dx = b-1
        m &= m - 1;
        uint32_t nk = (uint32_t)(nb + b - 1);
        uint32_t h = (nk * 2654435761u) >> shift;
        uint32_t j = 0xFFFFFFFFu;
        while (1) {
          u64 e = hash[h];
          if ((uint32_t)(e >> 32) == nk) { j = (uint32_t)e; break; }
          if (e == ~0ull) break;  // safety; bitmap hit implies present
          h = (h + 1) & hmask;
        }
        if (j == 0xFFFFFFFFu) continue;
        float4 f = feats[j];
        const float* w = &wl[((dz + 1) * 9 + (dy + 1) * 3 + b) * 64];
#pragma unroll
        for (int o = 0; o < 16; o++)
          acc[o] += f.x * w[o] + f.y * w[o + 16] + f.z * w[o + 32] +
                    f.w * w[o + 48];
      }
    }
  }

  float4* o4 = (float4*)(out + (size_t)i * 16);
  o4[0] = make_float4(acc[0], acc[1], acc[2], acc[3]);
  o4[1] = make_float4(acc[4], acc[5], acc[6], acc[7]);
  o4[2] = make_float4(acc[8], acc[9], acc[10], acc[11]);
  o4[3] = make_float4(acc[12], acc[13], acc[14], acc[15]);
}

// Channel-major coalesced reduction: lane reads out[g + k*T] (contiguous).
__global__ void __launch_bounds__(256) bn_reduce(const float* __restrict__ out,
                                                 float* __restrict__ accum,
                                                 int n) {
  __shared__ float s1[256], s2[256];
  int t = threadIdx.x;
  int g = blockIdx.x * 256 + t;
  int c = t & 15;
  int T = gridDim.x * 256;
  float sum = 0.f, sq = 0.f;
  for (int v = g >> 4; v < n; v += T >> 4) {
    float xv = out[v * 16 + c];
    sum += xv;
    sq += xv * xv;
  }
  s1[t] = sum;
  s2[t] = sq;
  __syncthreads();
  for (int s = 128; s >= 16; s >>= 1) {
    if (t < s) {
      s1[t] += s1[t + s];
      s2[t] += s2[t + s];
    }
    __syncthreads();
  }
  if (t < 16) {
    atomicAdd(&accum[t], s1[t]);
    atomicAdd(&accum[16 + t], s2[t]);
  }
}

__global__ void __launch_bounds__(256) bn_apply(
    float* __restrict__ out, const float* __restrict__ accum,
    const float* __restrict__ gamma, const float* __restrict__ beta, int n4,
    float invN) {
  __shared__ float sa[16], sb[16];
  int t = threadIdx.x;
  if (t < 16) {
    float mu = accum[t] * invN;
    float var = accum[16 + t] * invN - mu * mu;
    float inv = rsqrtf(var + BN_EPS);
    float a = gamma[t] * inv;
    sa[t] = a;
    sb[t] = beta[t] - mu * a;
  }
  __syncthreads();
  int i = blockIdx.x * 256 + t;
  if (i >= n4) return;
  float4* p = (float4*)out;
  float4 v = p[i];
  int c0 = (i & 3) * 4;
  v.x = fmaxf(v.x * sa[c0 + 0] + sb[c0 + 0], 0.f);
  v.y = fmaxf(v.y * sa[c0 + 1] + sb[c0 + 1], 0.f);
  v.z = fmaxf(v.z * sa[c0 + 2] + sb[c0 + 2], 0.f);
  v.w = fmaxf(v.w * sa[c0 + 3] + sb[c0 + 3], 0.f);
  p[i] = v;
}

extern "C" void kernel_launch(void* const* d_in, const int* in_sizes, int n_in,
                              void* d_out, int out_size, void* d_ws,
                              size_t ws_size, hipStream_t stream) {
  const float4* feats = (const float4*)d_in[0];
  const int4* coords = (const int4*)d_in[1];
  const float* weight = (const float*)d_in[2];
  const float* gamma = (const float*)d_in[3];
  const float* beta = (const float*)d_in[4];
  int n = in_sizes[0] / 4;

  int tblBits = 20;
  if ((8ull << tblBits) + (size_t)BM_WORDS * 8 + 256 > ws_size) tblBits = 19;
  int tblSize = 1 << tblBits;

  u64* hash = (u64*)d_ws;
  u64* bitmap = hash + tblSize;
  float* accum = (float*)(bitmap + BM_WORDS);

  int bb = (n + 255) / 256;
  hipLaunchKernelGGL(init_ws, dim3(2048), dim3(256), 0, stream, hash, bitmap,
                     accum, tblSize);
  hipLaunchKernelGGL(build_hash, dim3(bb), dim3(256), 0, stream, coords, hash,
                     bitmap, n, tblBits);
  hipLaunchKernelGGL(subm_conv, dim3(bb), dim3(256), 0, stream, feats, coords,
                     weight, hash, bitmap, (float*)d_out, n, tblBits);
  hipLaunchKernelGGL(bn_reduce, dim3(512), dim3(256), 0, stream,
                     (const float*)d_out, accum, n);
  int n4 = n * 4;
  hipLaunchKernelGGL(bn_apply, dim3((n4 + 255) / 256), dim3(256), 0, stream,
                     (float*)d_out, accum, gamma, beta, n4, 1.0f / n);
}